// Round 9
// baseline (76.172 us; speedup 1.0000x reference)
//
#include <hip/hip_runtime.h>
#include <math.h>

#define W 128
#define LROWS 22                   // 16 rows + 6 halo
#define TILE_IN 16
#define TILE_OUT 8
#define NTILES 8

typedef float f4 __attribute__((ext_vector_type(4)));
typedef float f2 __attribute__((ext_vector_type(2)));

__device__ __forceinline__ int refl128(int i) {
    i = (i < 0) ? (-1 - i) : i;    // symmetric (half-sample) reflect
    return (i > 127) ? (255 - i) : i;
}

// packed magnitude for two output columns at once
__device__ __forceinline__ f2 mag2(f2 re, f2 im) {
    f2 t = re * re + im * im + 1.0e-4f;
    f2 s = __builtin_elementwise_sqrt(t);
    return s - 0.01f;
}

__device__ __forceinline__ void st2v(float* p, f2 v) {
    __builtin_nontemporal_store(v, (f2*)p);
}

__global__ __launch_bounds__(256) void scat_j1_kernel(
    const float* __restrict__ x,
    float* __restrict__ out_ll,
    float* __restrict__ out_r)
{
    __shared__ float slo[LROWS][W];
    __shared__ float shi[LROWS][W];

    // XCD-chunked swizzle: grid 16384 = 8 * 2048, bijective.
    const int raw   = blockIdx.x;
    const int L_id  = (raw & 7) * 2048 + (raw >> 3);
    const int plane = L_id >> 3;       // n*64 + c   (0..2047)
    const int tile  = L_id & 7;        // 0..7
    const int r0    = tile * TILE_IN;
    const int tid   = threadIdx.x;

    const float* __restrict__ xp = x + (size_t)plane * (W * W);

    // ---- Phase 1: horizontal 5/7-tap filters; halo via lane shuffles ----
    {
        const int g  = tid & 31;       // 4-col group 0..31
        const int rb = tid >> 5;       // 0..7 row within pass
        #pragma unroll
        for (int it = 0; it < 3; ++it) {
            const int lr = it * 8 + rb;           // 0..23
            if (lr < LROWS) {
                const int q = refl128(r0 - 3 + lr);
                const f4* __restrict__ rv = (const f4*)(xp + (size_t)q * W);
                const f4 B = rv[g];               // cols 4g..4g+3 (only load)
                // neighbor halo from lanes g-1 / g+1 (width-32 groups == g groups)
                f4 A, C;
                A.y = __shfl_up(B.y, 1, 32);      // col 4g-3
                A.z = __shfl_up(B.z, 1, 32);      // col 4g-2
                A.w = __shfl_up(B.w, 1, 32);      // col 4g-1
                C.x = __shfl_down(B.x, 1, 32);    // col 4g+4
                C.y = __shfl_down(B.y, 1, 32);    // col 4g+5
                C.z = __shfl_down(B.z, 1, 32);    // col 4g+6
                const f4 revB = __builtin_shufflevector(B, B, 3, 2, 1, 0);
                if (g == 0)  A = revB;            // cols -3..-1 reflected
                if (g == 31) C = revB;            // cols 128..130 reflected
                // shifted windows over cols 4g-3 .. 4g+6 (register renames)
                const f4 m0 = __builtin_shufflevector(A, B, 1, 2, 3, 4);
                const f4 m1 = __builtin_shufflevector(A, B, 2, 3, 4, 5);
                const f4 m2 = __builtin_shufflevector(A, B, 3, 4, 5, 6);
                const f4 m3 = B;
                const f4 m4 = __builtin_shufflevector(B, C, 1, 2, 3, 4);
                const f4 m5 = __builtin_shufflevector(B, C, 2, 3, 4, 5);
                const f4 m6 = __builtin_shufflevector(B, C, 3, 4, 5, 6);
                const f4 s06 = m0 + m6;
                const f4 s15 = m1 + m5;
                const f4 s24 = m2 + m4;
                const f4 lo4 = -0.05f * s15 + 0.25f * s24 + 0.5f * m3;
                const f4 hi4 = -0.0107143f * s06 + 0.0535714f * s15
                             +  0.2607143f * s24 + -0.6071429f * m3;
                ((f4*)&slo[lr][0])[g] = lo4;
                ((f4*)&shi[lr][0])[g] = hi4;
            }
        }
    }
    __syncthreads();

    // ---- Phase 2: packed vertical filters + q2c + magnitudes + ll pool ----
    // thread = (col-pair cp 0..31 -> output cols 2cp,2cp+1; half-row Ib 0..7)
    const int cp = tid & 31;
    const int Ib = tid >> 5;
    const int R0 = 2 * Ib;             // LDS window start (7-tap top row)
    const int n  = plane >> 6;
    const int ch = plane & 63;

    // band taps folded with 1/sqrt(2); ll taps folded with 0.25
    const float S   = 0.70710678118654752f;
    const float a7  = -0.0107143f * S, b7 = 0.0535714f * S,
                c7  =  0.2607143f * S, d7 = -0.6071429f * S;
    const float a5s = -0.05f * S, b5s = 0.25f * S, c5s = 0.5f * S;
    const float p5a = -0.0125f, p5b = 0.0625f, p5c = 0.125f;

    f2 m15, m165, m45, m135, m75, m105, llv;
    {   // L band: lh (15/165) + ll
        f4 v0 = ((const f4*)&slo[R0 + 0][0])[cp];
        f4 v1 = ((const f4*)&slo[R0 + 1][0])[cp];
        f4 v2 = ((const f4*)&slo[R0 + 2][0])[cp];
        f4 v3 = ((const f4*)&slo[R0 + 3][0])[cp];
        f4 v4 = ((const f4*)&slo[R0 + 4][0])[cp];
        f4 v5 = ((const f4*)&slo[R0 + 5][0])[cp];
        f4 v6 = ((const f4*)&slo[R0 + 6][0])[cp];
        f4 v7 = ((const f4*)&slo[R0 + 7][0])[cp];
        const f4 s06 = v0 + v6, s15 = v1 + v5, s24 = v2 + v4;
        const f4 s17 = v1 + v7, s26 = v2 + v6, s35 = v3 + v5;
        const f4 t7 = a7 * s06 + b7 * s15 + c7 * s24 + d7 * v3;
        const f4 bo = a7 * s17 + b7 * s26 + c7 * s35 + d7 * v4;
        const f4 lt = p5a * s15 + p5b * s24 + p5c * v3;
        const f4 lb = p5a * s26 + p5b * s35 + p5c * v4;
        const f2 e  = __builtin_shufflevector(t7, t7, 0, 2);
        const f2 eo = __builtin_shufflevector(t7, t7, 1, 3);
        const f2 o  = __builtin_shufflevector(bo, bo, 1, 3);
        const f2 oo = __builtin_shufflevector(bo, bo, 0, 2);
        m15  = mag2(e - o, eo + oo);
        m165 = mag2(e + o, eo - oo);
        const f4 sl = lt + lb;
        llv.x = sl.x + sl.y;
        llv.y = sl.z + sl.w;
    }
    {   // H band: hh (45/135) + hl (75/105)
        f4 v0 = ((const f4*)&shi[R0 + 0][0])[cp];
        f4 v1 = ((const f4*)&shi[R0 + 1][0])[cp];
        f4 v2 = ((const f4*)&shi[R0 + 2][0])[cp];
        f4 v3 = ((const f4*)&shi[R0 + 3][0])[cp];
        f4 v4 = ((const f4*)&shi[R0 + 4][0])[cp];
        f4 v5 = ((const f4*)&shi[R0 + 5][0])[cp];
        f4 v6 = ((const f4*)&shi[R0 + 6][0])[cp];
        f4 v7 = ((const f4*)&shi[R0 + 7][0])[cp];
        const f4 s06 = v0 + v6, s15 = v1 + v5, s24 = v2 + v4;
        const f4 s17 = v1 + v7, s26 = v2 + v6, s35 = v3 + v5;
        const f4 t7 = a7 * s06 + b7 * s15 + c7 * s24 + d7 * v3;
        const f4 bo = a7 * s17 + b7 * s26 + c7 * s35 + d7 * v4;
        const f4 ht = a5s * s15 + b5s * s24 + c5s * v3;
        const f4 hb = a5s * s26 + b5s * s35 + c5s * v4;
        {
            const f2 e  = __builtin_shufflevector(t7, t7, 0, 2);
            const f2 eo = __builtin_shufflevector(t7, t7, 1, 3);
            const f2 o  = __builtin_shufflevector(bo, bo, 1, 3);
            const f2 oo = __builtin_shufflevector(bo, bo, 0, 2);
            m45  = mag2(e - o, eo + oo);
            m135 = mag2(e + o, eo - oo);
        }
        {
            const f2 e  = __builtin_shufflevector(ht, ht, 0, 2);
            const f2 eo = __builtin_shufflevector(ht, ht, 1, 3);
            const f2 o  = __builtin_shufflevector(hb, hb, 1, 3);
            const f2 oo = __builtin_shufflevector(hb, hb, 0, 2);
            m75  = mag2(e - o, eo + oo);
            m105 = mag2(e + o, eo - oo);
        }
    }

    const int I  = tile * TILE_OUT + Ib;
    const int J0 = 2 * cp;

    st2v(out_ll + (size_t)plane * 4096 + (size_t)I * 64 + J0, llv);

    float* rp = out_r + ((size_t)(n * 384 + ch)) * 4096 + (size_t)I * 64 + J0;
    st2v(rp + 0u * 262144u, m15);
    st2v(rp + 1u * 262144u, m45);
    st2v(rp + 2u * 262144u, m75);
    st2v(rp + 3u * 262144u, m105);
    st2v(rp + 4u * 262144u, m135);
    st2v(rp + 5u * 262144u, m165);
}

extern "C" void kernel_launch(void* const* d_in, const int* in_sizes, int n_in,
                              void* d_out, int out_size, void* d_ws, size_t ws_size,
                              hipStream_t stream) {
    const float* x = (const float*)d_in[0];
    float* out = (float*)d_out;
    float* out_ll = out;                 // 32*64*64*64 = 8388608 floats
    float* out_r  = out + 8388608;       // 32*384*64*64 = 50331648 floats

    dim3 grid(2048 * NTILES);            // (n*c) planes * 8 row-tiles
    dim3 block(256);
    hipLaunchKernelGGL(scat_j1_kernel, grid, block, 0, stream, x, out_ll, out_r);
}

// Round 10
// 75.663 us; speedup vs baseline: 1.0067x; 1.0067x over previous
//
#include <hip/hip_runtime.h>
#include <math.h>

#define W 128
#define LROWS 38                   // 32 rows + 6 halo
#define TILE_IN 32
#define TILE_OUT 16
#define NTILES 4

typedef float f4 __attribute__((ext_vector_type(4)));
typedef float f2 __attribute__((ext_vector_type(2)));

__device__ __forceinline__ int refl128(int i) {
    i = (i < 0) ? (-1 - i) : i;    // symmetric (half-sample) reflect
    return (i > 127) ? (255 - i) : i;
}

// packed magnitude for two output columns at once
__device__ __forceinline__ f2 mag2(f2 re, f2 im) {
    f2 t = re * re + im * im + 1.0e-4f;
    f2 s = __builtin_elementwise_sqrt(t);
    return s - 0.01f;
}

__device__ __forceinline__ void st2v(float* p, f2 v) {
    __builtin_nontemporal_store(v, (f2*)p);
}

// q2c + magnitudes: t = top full-res row (4 cols), b = bottom row
__device__ __forceinline__ void q2c(f4 t, f4 b, f2& mneg, f2& mpos) {
    const f2 e  = __builtin_shufflevector(t, t, 0, 2);
    const f2 eo = __builtin_shufflevector(t, t, 1, 3);
    const f2 o  = __builtin_shufflevector(b, b, 1, 3);
    const f2 oo = __builtin_shufflevector(b, b, 0, 2);
    mneg = mag2(e - o, eo + oo);
    mpos = mag2(e + o, eo - oo);
}

__global__ __launch_bounds__(256) void scat_j1_kernel(
    const float* __restrict__ x,
    float* __restrict__ out_ll,
    float* __restrict__ out_r)
{
    __shared__ float slo[LROWS][W];
    __shared__ float shi[LROWS][W];

    // XCD-chunked swizzle: grid 8192 = 8 * 1024, bijective.
    const int raw   = blockIdx.x;
    const int L_id  = (raw & 7) * 1024 + (raw >> 3);
    const int plane = L_id >> 2;       // n*64 + c   (0..2047)
    const int tile  = L_id & 3;        // 0..3
    const int r0    = tile * TILE_IN;
    const int tid   = threadIdx.x;

    const float* __restrict__ xp = x + (size_t)plane * (W * W);

    // ---- Phase 1: horizontal 5/7-tap filters (packed), write lo/hi to LDS ----
    {
        const int g  = tid & 31;       // 4-col group 0..31
        const int rb = tid >> 5;       // 0..7 row within pass
        #pragma unroll
        for (int it = 0; it < 5; ++it) {
            const int lr = it * 8 + rb;           // 0..39
            if (lr < LROWS) {                     // wave-uniform guard
                const int q = refl128(r0 - 3 + lr);
                const f4* __restrict__ rv = (const f4*)(xp + (size_t)q * W);
                const f4 B = rv[g];
                f4 A = rv[g > 0 ? g - 1 : 0];
                f4 C = rv[g < 31 ? g + 1 : 31];
                const f4 revB = __builtin_shufflevector(B, B, 3, 2, 1, 0);
                if (g == 0)  A = revB;            // cols -4..-1 reflected
                if (g == 31) C = revB;            // cols 128..131 reflected
                const f4 m0 = __builtin_shufflevector(A, B, 1, 2, 3, 4);
                const f4 m1 = __builtin_shufflevector(A, B, 2, 3, 4, 5);
                const f4 m2 = __builtin_shufflevector(A, B, 3, 4, 5, 6);
                const f4 m3 = B;
                const f4 m4 = __builtin_shufflevector(B, C, 1, 2, 3, 4);
                const f4 m5 = __builtin_shufflevector(B, C, 2, 3, 4, 5);
                const f4 m6 = __builtin_shufflevector(B, C, 3, 4, 5, 6);
                const f4 s06 = m0 + m6;
                const f4 s15 = m1 + m5;
                const f4 s24 = m2 + m4;
                const f4 lo4 = -0.05f * s15 + 0.25f * s24 + 0.5f * m3;
                const f4 hi4 = -0.0107143f * s06 + 0.0535714f * s15
                             +  0.2607143f * s24 + -0.6071429f * m3;
                ((f4*)&slo[lr][0])[g] = lo4;
                ((f4*)&shi[lr][0])[g] = hi4;
            }
        }
    }
    __syncthreads();

    // ---- Phase 2: 2 half-rows/thread from a 10-row register window ----
    // thread = (col-pair cp 0..31 -> output cols 2cp,2cp+1; Ib 0..7 -> half-rows 2Ib,2Ib+1)
    const int cp = tid & 31;
    const int Ib = tid >> 5;
    const int R0 = 4 * Ib;             // LDS window start
    const int n  = plane >> 6;
    const int ch = plane & 63;

    // band taps folded with 1/sqrt(2); ll taps folded with 0.25
    const float S   = 0.70710678118654752f;
    const float a7  = -0.0107143f * S, b7 = 0.0535714f * S,
                c7  =  0.2607143f * S, d7 = -0.6071429f * S;
    const float a5s = -0.05f * S, b5s = 0.25f * S, c5s = 0.5f * S;
    const float p5a = -0.0125f, p5b = 0.0625f, p5c = 0.125f;

    const int I0 = tile * TILE_OUT + 2 * Ib;
    float* llp = out_ll + (size_t)plane * 4096 + (size_t)I0 * 64 + 2 * cp;
    float* rp  = out_r + ((size_t)(n * 384 + ch)) * 4096 + (size_t)I0 * 64 + 2 * cp;

    {   // L band: lh (15/165) + ll
        f4 v[10];
        #pragma unroll
        for (int t = 0; t < 10; ++t) v[t] = ((const f4*)&slo[R0 + t][0])[cp];
        #pragma unroll
        for (int k = 0; k < 2; ++k) {
            const f4* w = v + 2 * k;   // window rows for half-row 2Ib+k
            const f4 s15 = w[1] + w[5], s24 = w[2] + w[4];
            const f4 s26 = w[2] + w[6], s35 = w[3] + w[5];
            const f4 t7 = a7 * (w[0] + w[6]) + b7 * s15 + c7 * s24 + d7 * w[3];
            const f4 bo = a7 * (w[1] + w[7]) + b7 * s26 + c7 * s35 + d7 * w[4];
            f2 m15, m165;
            q2c(t7, bo, m15, m165);
            const f4 lt = p5a * s15 + p5b * s24 + p5c * w[3];
            const f4 lb = p5a * s26 + p5b * s35 + p5c * w[4];
            const f4 sl = lt + lb;
            f2 llv;
            llv.x = sl.x + sl.y;
            llv.y = sl.z + sl.w;
            st2v(llp + k * 64, llv);
            st2v(rp + k * 64 + 0u * 262144u, m15);
            st2v(rp + k * 64 + 5u * 262144u, m165);
        }
    }
    {   // H band: hh (45/135) + hl (75/105)
        f4 v[10];
        #pragma unroll
        for (int t = 0; t < 10; ++t) v[t] = ((const f4*)&shi[R0 + t][0])[cp];
        #pragma unroll
        for (int k = 0; k < 2; ++k) {
            const f4* w = v + 2 * k;
            const f4 s15 = w[1] + w[5], s24 = w[2] + w[4];
            const f4 s26 = w[2] + w[6], s35 = w[3] + w[5];
            const f4 t7 = a7 * (w[0] + w[6]) + b7 * s15 + c7 * s24 + d7 * w[3];
            const f4 bo = a7 * (w[1] + w[7]) + b7 * s26 + c7 * s35 + d7 * w[4];
            f2 m45, m135;
            q2c(t7, bo, m45, m135);
            const f4 ht = a5s * s15 + b5s * s24 + c5s * w[3];
            const f4 hb = a5s * s26 + b5s * s35 + c5s * w[4];
            f2 m75, m105;
            q2c(ht, hb, m75, m105);
            st2v(rp + k * 64 + 1u * 262144u, m45);
            st2v(rp + k * 64 + 2u * 262144u, m75);
            st2v(rp + k * 64 + 3u * 262144u, m105);
            st2v(rp + k * 64 + 4u * 262144u, m135);
        }
    }
}

extern "C" void kernel_launch(void* const* d_in, const int* in_sizes, int n_in,
                              void* d_out, int out_size, void* d_ws, size_t ws_size,
                              hipStream_t stream) {
    const float* x = (const float*)d_in[0];
    float* out = (float*)d_out;
    float* out_ll = out;                 // 32*64*64*64 = 8388608 floats
    float* out_r  = out + 8388608;       // 32*384*64*64 = 50331648 floats

    dim3 grid(2048 * NTILES);            // (n*c) planes * 4 row-tiles
    dim3 block(256);
    hipLaunchKernelGGL(scat_j1_kernel, grid, block, 0, stream, x, out_ll, out_r);
}